// Round 10
// baseline (341.976 us; speedup 1.0000x reference)
//
#include <hip/hip_runtime.h>
#include <hip/hip_bf16.h>

// GQA block for MI355X. bf16 MFMA, fp32 accumulation.
// Pipeline:
//   prep: cvt X -> bf16 (Xb) + all weight transposes, ONE launch
//   gemm (m97 pattern, BK=64, XOR-swizzled LDS, global_load_lds staging, XCD-chunked
//     block swizzle): Qb [4096,2048] row-major; K -> Kf FRAGMENT-MAJOR
//     [g][b][d16][key][8]; V -> Vf FRAGMENT-MAJOR [g][b][slot8][d][8] (slot =
//     token-permuted bits2<->3, matching flash's PV slot order)
//   flash attention (32x32x16 MFMA): NO LDS, NO BARRIERS. 256-thr blocks, 4 waves =
//     4 heads of one group; K/V fragments loaded DIRECTLY from global (coalesced by
//     construction of Kf/Vf; L1/L2-resident). In-register softmax, mask fast-path,
//     softmax/PV half-pipeline. 1D grid decode pins each (g,b) to one XCD's L2.
//   gemm: out = Ab @ Wo + bo (fp32)

typedef __attribute__((ext_vector_type(8))) short short8;
typedef __attribute__((ext_vector_type(4))) short short4v;
typedef __attribute__((ext_vector_type(4))) float float4v;
typedef __attribute__((ext_vector_type(16))) float float16v;

#define C1F 0.12751743f   // (1/sqrt(128)) * log2(e)
#define B0F -16.0f        // fixed max offset in log2 units

#if defined(__has_builtin) && __has_builtin(__builtin_amdgcn_exp2f)
#define EXP2(x) __builtin_amdgcn_exp2f(x)
#else
#define EXP2(x) exp2f(x)
#endif

__device__ __forceinline__ short f2bf(float x) {
    __hip_bfloat16 h = __float2bfloat16(x);
    short s; __builtin_memcpy(&s, &h, sizeof(s)); return s;
}

__device__ __forceinline__ void gl16(const short* g, short* l) {
    __builtin_amdgcn_global_load_lds(
        (const __attribute__((address_space(1))) void*)g,
        (__attribute__((address_space(3))) void*)l, 16, 0, 0);
}

// ---------------- prep: X->bf16 AND weight transposes in ONE launch ----------------
__global__ __launch_bounds__(256) void prep_kernel(
    const float* __restrict__ X, short* __restrict__ Xb,
    const float* __restrict__ Wq, const float* __restrict__ Wk,
    const float* __restrict__ Wv, const float* __restrict__ Wo,
    short* __restrict__ WqkvT, short* __restrict__ Wot) {
    __shared__ float tile[32][33];
    const int bxg = blockIdx.x;
    if (bxg < 8192) {
        int i = (bxg * 256 + threadIdx.x) * 4;
        float4 v = *(const float4*)(X + i);
        short4v o;
        o[0] = f2bf(v.x); o[1] = f2bf(v.y); o[2] = f2bf(v.z); o[3] = f2bf(v.w);
        *(short4v*)(Xb + i) = o;
        return;
    }
    const int tid = bxg - 8192;
    int bx = tid % 160;
    const int k0 = (tid / 160) * 32;
    const float* W; short* Wt; int N;
    if (bx < 64)      { W = Wq; Wt = WqkvT;                      N = 2048; }
    else if (bx < 80) { W = Wk; Wt = WqkvT + (size_t)2048 * 2048; N = 512; bx -= 64; }
    else if (bx < 96) { W = Wv; Wt = WqkvT + (size_t)2560 * 2048; N = 512; bx -= 80; }
    else              { W = Wo; Wt = Wot;                        N = 2048; bx -= 96; }
    const int K = 2048;
    const int n0 = bx * 32;
    const int tx = threadIdx.x & 31, ty = threadIdx.x >> 5;
#pragma unroll
    for (int i = 0; i < 4; ++i) {
        int kk = ty + i * 8;
        tile[kk][tx] = W[(size_t)(k0 + kk) * N + n0 + tx];
    }
    __syncthreads();
#pragma unroll
    for (int i = 0; i < 4; ++i) {
        int nn = ty + i * 8;
        Wt[(size_t)(n0 + nn) * K + k0 + tx] = f2bf(tile[tx][nn]);
    }
}

// ---------------- GEMM: C = A[M,K] @ Bt[N,K]^T + bias ----------------
// 128x128 tile, BK=64, 4 waves, single-buffered (m97 2-barrier structure).
// LDS XOR-swizzled (T2, both sides). XCD-chunked block swizzle (T1).
// mode 0: fused QKV epilogue: Q->O0 [*,2048] row-major;
//         K->O1 = Kf [g][b][d16][key][8] fragment-major;
//         V->O2 = Vf [g][b][slot8][d][8] fragment-major (slot = token-permuted).
// mode 1: fp32 out Of [*,2048] + b0
__global__ __launch_bounds__(256) void gemm_dma_kernel(
    const short* __restrict__ A, const short* __restrict__ Bt,
    const float* __restrict__ b0, const float* __restrict__ b1, const float* __restrict__ b2,
    short* __restrict__ O0, short* __restrict__ O1, short* __restrict__ O2,
    float* __restrict__ Of, int K, int mode) {
    __shared__ short As[128 * 64];
    __shared__ short Bs[128 * 64];
    const int t = threadIdx.x, lane = t & 63, w = t >> 6;
    const int l15 = lane & 15, quad = lane >> 4;
    const int wm = (w & 1) * 64, wn = (w >> 1) * 64;

    // T1: XCD-chunked bijective remap (requires gridDim.x*gridDim.y % 8 == 0)
    const int nwg = gridDim.x * gridDim.y;
    int bid = blockIdx.y * gridDim.x + blockIdx.x;
    bid = (bid & 7) * (nwg >> 3) + (bid >> 3);
    const int m0 = (bid / gridDim.x) * 128, n0 = (bid % gridDim.x) * 128;

    const int r8 = lane >> 3;                        // 0..7 (== row&7 of staged row)
    const int csw = ((lane & 7) ^ r8) * 8;           // pre-swizzled source col (shorts)
    const short* ga = A + (size_t)(m0 + w * 8 + r8) * K + csw;
    const short* gb = Bt + (size_t)(n0 + w * 8 + r8) * K + csw;
    short* lA = As + (w * 8) * 64;   // wave-uniform LDS base; dst = base + lane*16B
    short* lB = Bs + (w * 8) * 64;
    const int xs = l15 & 7;                          // read-side row&7

    float4v acc[4][4] = {};

    for (int k0 = 0; k0 < K; k0 += 64) {
#pragma unroll
        for (int c = 0; c < 4; ++c) {
            gl16(ga + k0 + (size_t)(c * 32) * K, lA + c * 2048);
            gl16(gb + k0 + (size_t)(c * 32) * K, lB + c * 2048);
        }
        __syncthreads();   // drains vmcnt -> staging visible
#pragma unroll
        for (int ks = 0; ks < 2; ++ks) {
            short8 af[4], bfr[4];
            const int ps = ((ks * 4 + quad) ^ xs) * 8;
#pragma unroll
            for (int i = 0; i < 4; ++i)
                af[i] = *(const short8*)(As + (wm + i * 16 + l15) * 64 + ps);
#pragma unroll
            for (int j = 0; j < 4; ++j)
                bfr[j] = *(const short8*)(Bs + (wn + j * 16 + l15) * 64 + ps);
#pragma unroll
            for (int i = 0; i < 4; ++i)
#pragma unroll
                for (int j = 0; j < 4; ++j)
                    acc[i][j] = __builtin_amdgcn_mfma_f32_16x16x32_bf16(af[i], bfr[j], acc[i][j], 0, 0, 0);
        }
        __syncthreads();   // all reads done before next staging overwrite
    }

#pragma unroll
    for (int i = 0; i < 4; ++i) {
#pragma unroll
        for (int j = 0; j < 4; ++j) {
            const int col = n0 + wn + j * 16 + l15;
            const int row0 = m0 + wm + i * 16 + quad * 4;
            if (mode == 1) {
                const float bc = b0[col];
#pragma unroll
                for (int r = 0; r < 4; ++r)
                    Of[(size_t)(row0 + r) * 2048 + col] = acc[i][j][r] + bc;
            } else if (col < 2048) {
                const float bc = b0[col];
#pragma unroll
                for (int r = 0; r < 4; ++r)
                    O0[(size_t)(row0 + r) * 2048 + col] = f2bf(acc[i][j][r] + bc);
            } else if (col < 2560) {
                // K -> Kf [g][b][d16][key][8]
                const int c = col - 2048;                 // 0..511
                const int gk = c >> 7, d = c & 127;
                const int d16 = d >> 3, dj = d & 7;
                const float bc = b1[c];
#pragma unroll
                for (int r = 0; r < 4; ++r) {
                    const int tok = row0 + r;
                    const int bb = tok >> 11, key = tok & 2047;
                    O1[((size_t)((gk * 2 + bb) * 16 + d16) * 2048 + key) * 8 + dj] =
                        f2bf(acc[i][j][r] + bc);
                }
            } else {
                // V -> Vf [g][b][slot8][d][8], slot = token-permuted (bits 2<->3)
                const int c = col - 2560;                 // 0..511
                const int gv = c >> 7, d = c & 127;
                const float bc = b2[c];
                const int qsw = ((quad & 1) << 1) | (quad >> 1);
                const int slot0 = m0 + wm + i * 16 + qsw * 4;   // 4-aligned
                const int bb = slot0 >> 11, s = slot0 & 2047;
                const int sg = s >> 3, sj0 = s & 7;             // sj0 in {0,4}
                short4v ov;
#pragma unroll
                for (int r = 0; r < 4; ++r) ov[r] = f2bf(acc[i][j][r] + bc);
                *(short4v*)(O2 + ((size_t)((gv * 2 + bb) * 256 + sg) * 128 + d) * 8 + sj0) = ov;
            }
        }
    }
}

// ---------------- Flash attention: LDS-free, barrier-free ----------------
// grid 512 x 256 threads = 4 waves. bid decode: g = bid&3, b = (bid>>2)&1,
// qt = bid>>3  (same (g,b) -> same XCD under id%8 dispatch -> K/V L2-pinned).
// Wave w: head = g + 4*w. Swapped QK^T: st = mfma(Kfrag, Qfrag) -> st[reg] =
// S[key, q=lane&31], key = (reg&3)+8*(reg>>2)+4*(lane>>5) (+32 for st1).
// K-fragments from Kf, V-fragments from Vf: both coalesced (2x512B segments per
// load by layout construction). Softmax in-register; mask ballot deferred past
// QK^T; V preloaded at tile-top (latency under QK^T); NO __syncthreads anywhere.
__global__ __launch_bounds__(256, 2) void flash_kernel(
    const short* __restrict__ Qb, const short* __restrict__ Kf,
    const short* __restrict__ Vf, const int* __restrict__ mask,
    short* __restrict__ Ab) {
    const int t = threadIdx.x;
    const int lane = t & 63, w = t >> 6;            // w in 0..3
    const int l31 = lane & 31, hi = lane >> 5;
    const int bid = blockIdx.x;
    const int g = bid & 3, b = (bid >> 2) & 1, qt = bid >> 3;
    const int h = g + 4 * w;
    const int q0 = qt * 32;

    short8 qf[8];
#pragma unroll
    for (int dd = 0; dd < 8; ++dd)
        qf[dd] = *(const short8*)(Qb + (size_t)(b * 2048 + q0 + l31) * 2048
                                  + h * 128 + dd * 16 + hi * 8);

    float16v o[4] = {};
    float rsum = 0.f;

    // per-lane fragment bases (shorts)
    const short* kfl = Kf + (size_t)(g * 2 + b) * 16 * 2048 * 8 + hi * 16384 + l31 * 8;
    // per (dd, kb): + dd*32768 + kb*8 ; second key-half: +256
    const short* vfl = Vf + (size_t)(g * 2 + b) * 256 * 1024 + hi * 1024 + l31 * 8;
    // per (kb, cc, db): + kb*128 + cc*2048 + db*256
    const int* mp = mask + b * 2048 + lane;

    for (int kt = 0; kt < 32; ++kt) {
        const int kb = kt * 64;
        const int mvr = mp[kb];                     // issue early; ballot after QK^T

        // V preload for this tile (consumed by PV after QK^T + softmax)
        short8 vr[16];
#pragma unroll
        for (int cc = 0; cc < 4; ++cc)
#pragma unroll
            for (int db = 0; db < 4; ++db)
                vr[cc * 4 + db] = *(const short8*)(vfl + kb * 128 + cc * 2048 + db * 256);

        // S^T = K @ Q^T : st[reg] = S[key, q=l31]
        float16v st0 = {}, st1 = {};
        __builtin_amdgcn_s_setprio(1);
#pragma unroll
        for (int dd = 0; dd < 8; ++dd) {
            short8 kf0 = *(const short8*)(kfl + dd * 32768 + kb * 8);
            short8 kf1 = *(const short8*)(kfl + dd * 32768 + kb * 8 + 256);
            st0 = __builtin_amdgcn_mfma_f32_32x32x16_bf16(kf0, qf[dd], st0, 0, 0, 0);
            st1 = __builtin_amdgcn_mfma_f32_32x32x16_bf16(kf1, qf[dd], st1, 0, 0, 0);
        }
        __builtin_amdgcn_s_setprio(0);

        const unsigned long long bits = __ballot(mvr != 0);
        const bool full = (bits == ~0ull);
        const unsigned int mlo = ((unsigned int)bits) >> (4 * hi);
        const unsigned int mhi = ((unsigned int)(bits >> 32)) >> (4 * hi);

        // softmax half 0 (st0)
        if (full) {
#pragma unroll
            for (int e = 0; e < 16; ++e) {
                float p0 = EXP2(fmaf(st0[e], C1F, B0F));
                rsum += p0; st0[e] = p0;
            }
        } else {
#pragma unroll
            for (int e = 0; e < 16; ++e) {
                const int koff = (e & 3) + 8 * (e >> 2);
                float p0 = EXP2(fmaf(st0[e], C1F, B0F));
                p0 = ((mlo >> koff) & 1) ? p0 : 0.f;
                rsum += p0; st0[e] = p0;
            }
        }

        // PV half 0 (cc=0,1); softmax half 1 overlaps on VALU
        __builtin_amdgcn_s_setprio(1);
#pragma unroll
        for (int cc = 0; cc < 2; ++cc) {
            short8 pa;
#pragma unroll
            for (int e = 0; e < 8; ++e) pa[e] = f2bf(st0[cc * 8 + e]);
#pragma unroll
            for (int db = 0; db < 4; ++db)
                o[db] = __builtin_amdgcn_mfma_f32_32x32x16_bf16(pa, vr[cc * 4 + db], o[db], 0, 0, 0);
        }
        __builtin_amdgcn_s_setprio(0);

        // softmax half 1 (st1)
        if (full) {
#pragma unroll
            for (int e = 0; e < 16; ++e) {
                float p1 = EXP2(fmaf(st1[e], C1F, B0F));
                rsum += p1; st1[e] = p1;
            }
        } else {
#pragma unroll
            for (int e = 0; e < 16; ++e) {
                const int koff = (e & 3) + 8 * (e >> 2);
                float p1 = EXP2(fmaf(st1[e], C1F, B0F));
                p1 = ((mhi >> koff) & 1) ? p1 : 0.f;
                rsum += p1; st1[e] = p1;
            }
        }

        // PV half 1 (cc=2,3)
        __builtin_amdgcn_s_setprio(1);
#pragma unroll
        for (int cc = 2; cc < 4; ++cc) {
            short8 pa;
#pragma unroll
            for (int e = 0; e < 8; ++e) pa[e] = f2bf(st1[(cc & 1) * 8 + e]);
#pragma unroll
            for (int db = 0; db < 4; ++db)
                o[db] = __builtin_amdgcn_mfma_f32_32x32x16_bf16(pa, vr[cc * 4 + db], o[db], 0, 0, 0);
        }
        __builtin_amdgcn_s_setprio(0);
    }

    rsum += __shfl_xor(rsum, 32, 64);
    const float rinv = (rsum > 0.f) ? 1.f / rsum : 0.f;
    float rq[16];
#pragma unroll
    for (int e = 0; e < 16; ++e) {
        const int koff = (e & 3) + 8 * (e >> 2);
        rq[e] = __shfl(rinv, koff + 4 * hi, 64);
    }
    const size_t ob = (size_t)(b * 2048 + q0) * 2048 + h * 128;
#pragma unroll
    for (int db = 0; db < 4; ++db)
#pragma unroll
        for (int e = 0; e < 16; ++e) {
            const int koff = (e & 3) + 8 * (e >> 2);
            Ab[ob + (size_t)(koff + 4 * hi) * 2048 + db * 32 + l31] =
                f2bf(o[db][e] * rq[e]);
        }
}

extern "C" void kernel_launch(void* const* d_in, const int* in_sizes, int n_in,
                              void* d_out, int out_size, void* d_ws, size_t ws_size,
                              hipStream_t stream) {
    (void)in_sizes; (void)n_in; (void)out_size; (void)ws_size;
    const float* X  = (const float*)d_in[0];
    const int* mask = (const int*)d_in[1];
    const float* Wq = (const float*)d_in[2];
    const float* bq = (const float*)d_in[3];
    const float* Wk = (const float*)d_in[4];
    const float* bk = (const float*)d_in[5];
    const float* Wv = (const float*)d_in[6];
    const float* bv = (const float*)d_in[7];
    const float* Wo = (const float*)d_in[8];
    const float* bo = (const float*)d_in[9];
    float* out = (float*)d_out;

    char* ws = (char*)d_ws;
    short* Xb     = (short*)(ws + 0);          // 16,777,216 B (reused as Ab)
    short* WqkvT  = (short*)(ws + 16777216);   // 12,582,912 B [3072,2048]
    short* Wot    = (short*)(ws + 29360128);   //  8,388,608 B
    short* Qb     = (short*)(ws + 37748736);   // 16,777,216 B
    short* Kf     = (short*)(ws + 54525952);   //  4,194,304 B  [4][2][16][2048][8]
    short* Vf     = (short*)(ws + 58720256);   //  4,194,304 B  [4][2][256][128][8]
    short* Ab     = Xb;

    const int HID = 2048;

    // cvt (8192 blocks) + all transposes (10240 blocks) in one launch
    prep_kernel<<<18432, 256, 0, stream>>>(X, Xb, Wq, Wk, Wv, Wo, WqkvT, Wot);

    // fused Q|K|V projection: N = 3072 (768 blocks, %8==0 for T1)
    gemm_dma_kernel<<<dim3(24, 32), 256, 0, stream>>>(
        Xb, WqkvT, bq, bk, bv, Qb, Kf, Vf, nullptr, HID, 0);

    flash_kernel<<<512, 256, 0, stream>>>(Qb, Kf, Vf, mask, Ab);

    // out = Ab @ Wo + bo (512 blocks, %8==0 for T1)
    gemm_dma_kernel<<<dim3(16, 32), 256, 0, stream>>>(
        Ab, Wot, bo, nullptr, nullptr, nullptr, nullptr, nullptr, out, HID, 1);
}

// Round 11
// 314.702 us; speedup vs baseline: 1.0867x; 1.0867x over previous
//
#include <hip/hip_runtime.h>
#include <hip/hip_bf16.h>

// GQA block for MI355X. bf16 MFMA, fp32 accumulation.
// Pipeline:
//   prep: cvt X -> bf16 (Xb) + all weight transposes, ONE launch
//   gemm (m97 pattern, BK=64, XOR-swizzled LDS, global_load_lds staging, XCD-chunked
//     block swizzle): Qb [4096,2048], Kb [4096,512], Vt [512,4096] (V transposed +
//     token-permuted bits2<->3 for flash PV slot order)
//   flash attention (32x32x16 MFMA): 256-thr blocks (4 waves = 4 heads of one group),
//     swapped QK^T, in-register softmax, double-buffered K/V staged via
//     global_load_lds DMA (pre-swizzled source + XOR-swizzled reads; no ds_writes,
//     LDS instrs 40->32 per wave-tile), 1 barrier/tile, mask fast-path,
//     softmax/PV half-pipeline.
//   gemm: out = Ab @ Wo + bo (fp32)

typedef __attribute__((ext_vector_type(8))) short short8;
typedef __attribute__((ext_vector_type(4))) short short4v;
typedef __attribute__((ext_vector_type(4))) float float4v;
typedef __attribute__((ext_vector_type(16))) float float16v;

#define C1F 0.12751743f   // (1/sqrt(128)) * log2(e)
#define B0F -16.0f        // fixed max offset in log2 units

#if defined(__has_builtin) && __has_builtin(__builtin_amdgcn_exp2f)
#define EXP2(x) __builtin_amdgcn_exp2f(x)
#else
#define EXP2(x) exp2f(x)
#endif

__device__ __forceinline__ short f2bf(float x) {
    __hip_bfloat16 h = __float2bfloat16(x);
    short s; __builtin_memcpy(&s, &h, sizeof(s)); return s;
}

__device__ __forceinline__ void gl16(const short* g, short* l) {
    __builtin_amdgcn_global_load_lds(
        (const __attribute__((address_space(1))) void*)g,
        (__attribute__((address_space(3))) void*)l, 16, 0, 0);
}

// ---------------- prep: X->bf16 AND weight transposes in ONE launch ----------------
__global__ __launch_bounds__(256) void prep_kernel(
    const float* __restrict__ X, short* __restrict__ Xb,
    const float* __restrict__ Wq, const float* __restrict__ Wk,
    const float* __restrict__ Wv, const float* __restrict__ Wo,
    short* __restrict__ WqkvT, short* __restrict__ Wot) {
    __shared__ float tile[32][33];
    const int bxg = blockIdx.x;
    if (bxg < 8192) {
        int i = (bxg * 256 + threadIdx.x) * 4;
        float4 v = *(const float4*)(X + i);
        short4v o;
        o[0] = f2bf(v.x); o[1] = f2bf(v.y); o[2] = f2bf(v.z); o[3] = f2bf(v.w);
        *(short4v*)(Xb + i) = o;
        return;
    }
    const int tid = bxg - 8192;
    int bx = tid % 160;
    const int k0 = (tid / 160) * 32;
    const float* W; short* Wt; int N;
    if (bx < 64)      { W = Wq; Wt = WqkvT;                      N = 2048; }
    else if (bx < 80) { W = Wk; Wt = WqkvT + (size_t)2048 * 2048; N = 512; bx -= 64; }
    else if (bx < 96) { W = Wv; Wt = WqkvT + (size_t)2560 * 2048; N = 512; bx -= 80; }
    else              { W = Wo; Wt = Wot;                        N = 2048; bx -= 96; }
    const int K = 2048;
    const int n0 = bx * 32;
    const int tx = threadIdx.x & 31, ty = threadIdx.x >> 5;
#pragma unroll
    for (int i = 0; i < 4; ++i) {
        int kk = ty + i * 8;
        tile[kk][tx] = W[(size_t)(k0 + kk) * N + n0 + tx];
    }
    __syncthreads();
#pragma unroll
    for (int i = 0; i < 4; ++i) {
        int nn = ty + i * 8;
        Wt[(size_t)(n0 + nn) * K + k0 + tx] = f2bf(tile[tx][nn]);
    }
}

// ---------------- GEMM: C = A[M,K] @ Bt[N,K]^T + bias ----------------
// 128x128 tile, BK=64, 4 waves, single-buffered (m97 2-barrier structure).
// LDS XOR-swizzled (T2, both sides). XCD-chunked block swizzle (T1).
// mode 0: fused QKV epilogue (Q->O0, K->O1 [4096,512], V->O2 transposed [512,4096]
//         + within-16 token permute bits2<->3)
// mode 1: fp32 out Of [*,2048] + b0
__global__ __launch_bounds__(256) void gemm_dma_kernel(
    const short* __restrict__ A, const short* __restrict__ Bt,
    const float* __restrict__ b0, const float* __restrict__ b1, const float* __restrict__ b2,
    short* __restrict__ O0, short* __restrict__ O1, short* __restrict__ O2,
    float* __restrict__ Of, int K, int mode) {
    __shared__ short As[128 * 64];
    __shared__ short Bs[128 * 64];
    const int t = threadIdx.x, lane = t & 63, w = t >> 6;
    const int l15 = lane & 15, quad = lane >> 4;
    const int wm = (w & 1) * 64, wn = (w >> 1) * 64;

    // T1: XCD-chunked bijective remap (requires gridDim.x*gridDim.y % 8 == 0)
    const int nwg = gridDim.x * gridDim.y;
    int bid = blockIdx.y * gridDim.x + blockIdx.x;
    bid = (bid & 7) * (nwg >> 3) + (bid >> 3);
    const int m0 = (bid / gridDim.x) * 128, n0 = (bid % gridDim.x) * 128;

    const int r8 = lane >> 3;                        // 0..7 (== row&7 of staged row)
    const int csw = ((lane & 7) ^ r8) * 8;           // pre-swizzled source col (shorts)
    const short* ga = A + (size_t)(m0 + w * 8 + r8) * K + csw;
    const short* gb = Bt + (size_t)(n0 + w * 8 + r8) * K + csw;
    short* lA = As + (w * 8) * 64;   // wave-uniform LDS base; dst = base + lane*16B
    short* lB = Bs + (w * 8) * 64;
    const int xs = l15 & 7;                          // read-side row&7

    float4v acc[4][4] = {};

    for (int k0 = 0; k0 < K; k0 += 64) {
#pragma unroll
        for (int c = 0; c < 4; ++c) {
            gl16(ga + k0 + (size_t)(c * 32) * K, lA + c * 2048);
            gl16(gb + k0 + (size_t)(c * 32) * K, lB + c * 2048);
        }
        __syncthreads();   // drains vmcnt -> staging visible
#pragma unroll
        for (int ks = 0; ks < 2; ++ks) {
            short8 af[4], bfr[4];
            const int ps = ((ks * 4 + quad) ^ xs) * 8;
#pragma unroll
            for (int i = 0; i < 4; ++i)
                af[i] = *(const short8*)(As + (wm + i * 16 + l15) * 64 + ps);
#pragma unroll
            for (int j = 0; j < 4; ++j)
                bfr[j] = *(const short8*)(Bs + (wn + j * 16 + l15) * 64 + ps);
#pragma unroll
            for (int i = 0; i < 4; ++i)
#pragma unroll
                for (int j = 0; j < 4; ++j)
                    acc[i][j] = __builtin_amdgcn_mfma_f32_16x16x32_bf16(af[i], bfr[j], acc[i][j], 0, 0, 0);
        }
        __syncthreads();   // all reads done before next staging overwrite
    }

#pragma unroll
    for (int i = 0; i < 4; ++i) {
#pragma unroll
        for (int j = 0; j < 4; ++j) {
            const int col = n0 + wn + j * 16 + l15;
            const int row0 = m0 + wm + i * 16 + quad * 4;
            if (mode == 1) {
                const float bc = b0[col];
#pragma unroll
                for (int r = 0; r < 4; ++r)
                    Of[(size_t)(row0 + r) * 2048 + col] = acc[i][j][r] + bc;
            } else if (col < 2048) {
                const float bc = b0[col];
#pragma unroll
                for (int r = 0; r < 4; ++r)
                    O0[(size_t)(row0 + r) * 2048 + col] = f2bf(acc[i][j][r] + bc);
            } else if (col < 2560) {
                const int c = col - 2048;
                const float bc = b1[c];
#pragma unroll
                for (int r = 0; r < 4; ++r)
                    O1[(size_t)(row0 + r) * 512 + c] = f2bf(acc[i][j][r] + bc);
            } else {
                const int c = col - 2560;
                const float bc = b2[c];
                // token permutation for flash PV slot order: bits 2<->3 of within-16 index
                const int qsw = ((quad & 1) << 1) | (quad >> 1);
                const int prow = m0 + wm + i * 16 + qsw * 4;
                short4v ov;
#pragma unroll
                for (int r = 0; r < 4; ++r) ov[r] = f2bf(acc[i][j][r] + bc);
                *(short4v*)(O2 + (size_t)c * 4096 + prow) = ov;   // 4 consecutive rows
            }
        }
    }
}

// ---------------- Flash attention, 32x32 MFMA, DMA-staged K/V ----------------
// grid (S/32, G, B), 256 threads = 4 waves. Wave w: head = g + 4*w.
// Swapped QK^T: st = mfma(Kfrag, Qfrag) -> st[reg] = S[key, q=lane&31] with
// key = (reg&3)+8*(reg>>2)+4*(lane>>5) (+32 for st1). Softmax in-register.
// K/V staged via global_load_lds DMA into LINEAR double buffers with XOR swizzle:
//   Ks[key][pc], pc = gc ^ (key&7)  (16B chunks, gc = global d-chunk)
//   Vs[d][pc],  pc = gc ^ (d&7)    (16B chunks, gc = global slot-chunk)
// Source global addresses pre-swizzled per-lane; reads apply the same XOR ->
// both-sides-or-neither (rule 21). NO ds_write instructions; 1 barrier/tile;
// DMA for kt+1 issued at compute top of kt. Mask fast-path; half-pipeline.
__global__ __launch_bounds__(256, 2) void flash_kernel(
    const short* __restrict__ Qb, const short* __restrict__ Kb,
    const short* __restrict__ Vt, const int* __restrict__ mask,
    short* __restrict__ Ab) {
    __shared__ short Ks[2][64 * 128];   // linear, swizzled content (32 KB)
    __shared__ short Vs[2][128 * 64];   // linear, swizzled content (32 KB)

    const int t = threadIdx.x;
    const int lane = t & 63, w = t >> 6;            // w in 0..3
    const int l31 = lane & 31, hi = lane >> 5;
    const int qt = blockIdx.x, g = blockIdx.y, b = blockIdx.z;
    const int h = g + 4 * w;
    const int q0 = qt * 32;

    short8 qf[8];
#pragma unroll
    for (int dd = 0; dd < 8; ++dd)
        qf[dd] = *(const short8*)(Qb + (size_t)(b * 2048 + q0 + l31) * 2048
                                  + h * 128 + dd * 16 + hi * 8);

    float16v o[4] = {};
    float rsum = 0.f;

    // K staging geometry: call i covers rows i*16 + w*4 + (lane>>4), phys chunk lane&15.
    const int krow = w * 4 + (lane >> 4);            // + i*16
    const int kgc = (lane & 15) ^ (krow & 7);        // global d-chunk (i*16 = 0 mod 8)
    const short* kgsrc = Kb + (size_t)(b * 2048 + krow) * 512 + g * 128 + kgc * 8;
    // V staging geometry: call i covers d = i*32 + w*8 + (lane>>3), phys chunk lane&7.
    const int vrow = w * 8 + (lane >> 3);            // + i*32
    const int vgc = (lane & 7) ^ (vrow & 7);         // global slot-chunk
    const short* vgsrc = Vt + (size_t)(g * 128 + vrow) * 4096 + b * 2048 + vgc * 8;
    const int* mp = mask + b * 2048 + lane;
    const int xk = l31 & 7;                          // read-side XOR (row&7)

#define STAGE_DMA(BUF, KB)                                                         \
    do {                                                                           \
        short* KsB = &Ks[BUF][w * 512];                                            \
        short* VsB = &Vs[BUF][w * 512];                                            \
        _Pragma("unroll")                                                          \
        for (int i_ = 0; i_ < 4; ++i_)                                             \
            gl16(kgsrc + (size_t)((KB) + i_ * 16) * 512, KsB + i_ * 2048);         \
        _Pragma("unroll")                                                          \
        for (int i_ = 0; i_ < 4; ++i_)                                             \
            gl16(vgsrc + (KB) + (size_t)(i_ * 32) * 4096, VsB + i_ * 2048);        \
    } while (0)

    STAGE_DMA(0, 0);
    int mvr = mp[0];
    __syncthreads();   // buf0 DMA complete

    int cur = 0;

    for (int kt = 0; kt < 32; ++kt) {
        int mvr_next = 0;
        if (kt + 1 < 32) {
            STAGE_DMA(cur ^ 1, (kt + 1) * 64);   // DMA lands during this tile's compute
            mvr_next = mp[(kt + 1) * 64];
        }
        const short* Ksb = &Ks[cur][0];
        const short* Vsb = &Vs[cur][0];

        // S^T = K @ Q^T : st[reg] = S[key, q=l31]
        float16v st0 = {}, st1 = {};
        __builtin_amdgcn_s_setprio(1);
#pragma unroll
        for (int dd = 0; dd < 8; ++dd) {
            const int c0 = ((dd * 2 + hi) ^ xk) * 8;
            short8 kf0 = *(const short8*)(Ksb + l31 * 128 + c0);
            short8 kf1 = *(const short8*)(Ksb + (32 + l31) * 128 + c0);
            st0 = __builtin_amdgcn_mfma_f32_32x32x16_bf16(kf0, qf[dd], st0, 0, 0, 0);
            st1 = __builtin_amdgcn_mfma_f32_32x32x16_bf16(kf1, qf[dd], st1, 0, 0, 0);
        }
        __builtin_amdgcn_s_setprio(0);

        const unsigned long long bits = __ballot(mvr != 0);
        const bool full = (bits == ~0ull);
        const unsigned int mlo = ((unsigned int)bits) >> (4 * hi);
        const unsigned int mhi = ((unsigned int)(bits >> 32)) >> (4 * hi);

        // softmax half 0 (st0)
        if (full) {
#pragma unroll
            for (int e = 0; e < 16; ++e) {
                float p0 = EXP2(fmaf(st0[e], C1F, B0F));
                rsum += p0; st0[e] = p0;
            }
        } else {
#pragma unroll
            for (int e = 0; e < 16; ++e) {
                const int koff = (e & 3) + 8 * (e >> 2);
                float p0 = EXP2(fmaf(st0[e], C1F, B0F));
                p0 = ((mlo >> koff) & 1) ? p0 : 0.f;
                rsum += p0; st0[e] = p0;
            }
        }

        // PV half 0 (cc=0,1); softmax half 1 overlaps on VALU
        __builtin_amdgcn_s_setprio(1);
#pragma unroll
        for (int cc = 0; cc < 2; ++cc) {
            short8 pa;
#pragma unroll
            for (int e = 0; e < 8; ++e) pa[e] = f2bf(st0[cc * 8 + e]);
#pragma unroll
            for (int db = 0; db < 4; ++db) {
                const int vc = ((cc * 2 + hi) ^ xk) * 8;
                short8 vb = *(const short8*)(Vsb + (db * 32 + l31) * 64 + vc);
                o[db] = __builtin_amdgcn_mfma_f32_32x32x16_bf16(pa, vb, o[db], 0, 0, 0);
            }
        }
        __builtin_amdgcn_s_setprio(0);

        // softmax half 1 (st1)
        if (full) {
#pragma unroll
            for (int e = 0; e < 16; ++e) {
                float p1 = EXP2(fmaf(st1[e], C1F, B0F));
                rsum += p1; st1[e] = p1;
            }
        } else {
#pragma unroll
            for (int e = 0; e < 16; ++e) {
                const int koff = (e & 3) + 8 * (e >> 2);
                float p1 = EXP2(fmaf(st1[e], C1F, B0F));
                p1 = ((mhi >> koff) & 1) ? p1 : 0.f;
                rsum += p1; st1[e] = p1;
            }
        }

        // PV half 1 (cc=2,3)
        __builtin_amdgcn_s_setprio(1);
#pragma unroll
        for (int cc = 2; cc < 4; ++cc) {
            short8 pa;
#pragma unroll
            for (int e = 0; e < 8; ++e) pa[e] = f2bf(st1[(cc & 1) * 8 + e]);
#pragma unroll
            for (int db = 0; db < 4; ++db) {
                const int vc = ((cc * 2 + hi) ^ xk) * 8;
                short8 vb = *(const short8*)(Vsb + (db * 32 + l31) * 64 + vc);
                o[db] = __builtin_amdgcn_mfma_f32_32x32x16_bf16(pa, vb, o[db], 0, 0, 0);
            }
        }
        __builtin_amdgcn_s_setprio(0);

        __syncthreads();   // drains vmcnt (kt+1 DMA done) + all reads of buf[cur] done
        mvr = mvr_next;
        cur ^= 1;
    }
#undef STAGE_DMA

    rsum += __shfl_xor(rsum, 32, 64);
    const float rinv = (rsum > 0.f) ? 1.f / rsum : 0.f;
    float rq[16];
#pragma unroll
    for (int e = 0; e < 16; ++e) {
        const int koff = (e & 3) + 8 * (e >> 2);
        rq[e] = __shfl(rinv, koff + 4 * hi, 64);
    }
    const size_t ob = (size_t)(b * 2048 + q0) * 2048 + h * 128;
#pragma unroll
    for (int db = 0; db < 4; ++db)
#pragma unroll
        for (int e = 0; e < 16; ++e) {
            const int koff = (e & 3) + 8 * (e >> 2);
            Ab[ob + (size_t)(koff + 4 * hi) * 2048 + db * 32 + l31] =
                f2bf(o[db][e] * rq[e]);
        }
}

extern "C" void kernel_launch(void* const* d_in, const int* in_sizes, int n_in,
                              void* d_out, int out_size, void* d_ws, size_t ws_size,
                              hipStream_t stream) {
    (void)in_sizes; (void)n_in; (void)out_size; (void)ws_size;
    const float* X  = (const float*)d_in[0];
    const int* mask = (const int*)d_in[1];
    const float* Wq = (const float*)d_in[2];
    const float* bq = (const float*)d_in[3];
    const float* Wk = (const float*)d_in[4];
    const float* bk = (const float*)d_in[5];
    const float* Wv = (const float*)d_in[6];
    const float* bv = (const float*)d_in[7];
    const float* Wo = (const float*)d_in[8];
    const float* bo = (const float*)d_in[9];
    float* out = (float*)d_out;

    char* ws = (char*)d_ws;
    short* Xb     = (short*)(ws + 0);          // 16,777,216 B (reused as Ab)
    short* WqkvT  = (short*)(ws + 16777216);   // 12,582,912 B [3072,2048]
    short* Wot    = (short*)(ws + 29360128);   //  8,388,608 B
    short* Qb     = (short*)(ws + 37748736);   // 16,777,216 B
    short* Kb     = (short*)(ws + 54525952);   //  4,194,304 B [4096,512]
    short* Vt     = (short*)(ws + 58720256);   //  4,194,304 B [512,4096]
    short* Ab     = Xb;

    const int HID = 2048;

    // cvt (8192 blocks) + all transposes (10240 blocks) in one launch
    prep_kernel<<<18432, 256, 0, stream>>>(X, Xb, Wq, Wk, Wv, Wo, WqkvT, Wot);

    // fused Q|K|V projection: N = 3072 (768 blocks, %8==0 for T1)
    gemm_dma_kernel<<<dim3(24, 32), 256, 0, stream>>>(
        Xb, WqkvT, bq, bk, bv, Qb, Kb, Vt, nullptr, HID, 0);

    flash_kernel<<<dim3(64, 4, 2), 256, 0, stream>>>(Qb, Kb, Vt, mask, Ab);

    // out = Ab @ Wo + bo (512 blocks, %8==0 for T1)
    gemm_dma_kernel<<<dim3(16, 32), 256, 0, stream>>>(
        Ab, Wot, bo, nullptr, nullptr, nullptr, nullptr, nullptr, out, HID, 1);
}